// Round 4
// baseline (316.695 us; speedup 1.0000x reference)
//
#include <hip/hip_runtime.h>
#include <hip/hip_bf16.h>
#include <stdint.h>

// Problem constants (from reference)
#define DMODEL 1024
#define M_TOK  16384   // B*L = 4*4096

typedef __attribute__((ext_vector_type(8))) short short8;   // 8 x bf16 (4 VGPRs)
typedef __attribute__((ext_vector_type(4))) float f32x4;    // MFMA C/D frag

// Pack two fp32 -> two bf16 (RNE) in one dword via v_perm_b32.
__device__ __forceinline__ unsigned int pack2_bf16(float f0, float f1) {
    unsigned int u0 = __builtin_bit_cast(unsigned int, f0);
    unsigned int u1 = __builtin_bit_cast(unsigned int, f1);
    u0 += 0x7fffu + ((u0 >> 16) & 1u);
    u1 += 0x7fffu + ((u1 >> 16) & 1u);
    return __builtin_amdgcn_perm(u1, u0, 0x07060302);  // mem order f0, f1
}

// async global->LDS, 16B per lane. LDS dest = wave-uniform base + lane*16.
__device__ __forceinline__ void gload_lds16(const void* g, void* l) {
    __builtin_amdgcn_global_load_lds(
        (const __attribute__((address_space(1))) void*)g,
        (__attribute__((address_space(3))) void*)l, 16, 0, 0);
}

// ---------------- Phase 0: zero the compaction counter ----------------------
// ws is re-poisoned every call; graph-safe 1-thread zeroing (no memset node).
__global__ void zero_ctr(int* __restrict__ n_agent) { *n_agent = 0; }

// ---------------- Phase 1: gather + convert + atomic compaction -------------
// 1024 threads = 16 waves, one 1024-float row per wave. Block counts its
// agent rows, takes ONE atomicAdd for a contiguous slot range (order across
// blocks is nondeterministic, but each row's result is slot-independent).
// Agent rows -> bf16 Xc[slot]; user rows -> exact fp32 copy to out.
// Trailing 64 blocks convert R -> bf16 Rb.
__global__ void __launch_bounds__(1024)
gather3(const int* __restrict__ ids, const int* __restrict__ roles,
        const float* __restrict__ emb, const float* __restrict__ Rm,
        __hip_bfloat16* __restrict__ Xc, __hip_bfloat16* __restrict__ Rb,
        float* __restrict__ out, int* __restrict__ orig,
        int* __restrict__ n_agent) {
    __shared__ int s_cnt[16];
    __shared__ int s_slot[16];
    const int wave = threadIdx.x >> 6;
    const int lane = threadIdx.x & 63;
    const int blk  = blockIdx.x;
    if (blk < M_TOK / 16) {
        const int row  = blk * 16 + wave;
        const int id   = ids[row];                 // wave-uniform (s_load)
        const int role = roles[row];
        if (lane == 0) s_cnt[wave] = (role == 1);
        __syncthreads();
        if (threadIdx.x == 0) {
            int tot = 0, pre[16];
#pragma unroll
            for (int w = 0; w < 16; ++w) { pre[w] = tot; tot += s_cnt[w]; }
            const int base = atomicAdd(n_agent, tot);   // one atomic per block
#pragma unroll
            for (int w = 0; w < 16; ++w) s_slot[w] = base + pre[w];
        }
        __syncthreads();
        const float* src = emb + (size_t)id * DMODEL;
        if (role == 1) {
            const int slot = s_slot[wave];
            if (lane == 0) orig[slot] = row;
            unsigned short* dst = (unsigned short*)(Xc + (size_t)slot * DMODEL);
#pragma unroll
            for (int c = 0; c < 4; ++c) {
                const int idx = c * 256 + lane * 4;
                float4 v = *(const float4*)(src + idx);
                uint2 p = make_uint2(pack2_bf16(v.x, v.y), pack2_bf16(v.z, v.w));
                *(uint2*)(dst + idx) = p;
            }
        } else {
            float* dst = out + (size_t)row * DMODEL;
#pragma unroll
            for (int c = 0; c < 4; ++c) {
                const int idx = c * 256 + lane * 4;
                *(float4*)(dst + idx) = *(const float4*)(src + idx);
            }
        }
    } else {
        const int r = (blk - M_TOK / 16) * 16 + wave;
        const float* src = Rm + (size_t)r * DMODEL;
        unsigned short* dst = (unsigned short*)(Rb + (size_t)r * DMODEL);
#pragma unroll
        for (int c = 0; c < 4; ++c) {
            const int idx = c * 256 + lane * 4;
            float4 v = *(const float4*)(src + idx);
            uint2 p = make_uint2(pack2_bf16(v.x, v.y), pack2_bf16(v.z, v.w));
            *(uint2*)(dst + idx) = p;
        }
    }
}

// ---------------- Phase 2: bf16 GEMM over compacted agent rows --------------
// C[orig[j], e] = sum_d Xc[j,d] * R[e,d].  128x128 tile (r2 geometry, best
// measured), BK=64, depth-2 pipeline with COUNTED vmcnt (T3/T4-lite): each
// wave keeps the next tile's 8 global_load_lds in flight across the barrier;
// `s_waitcnt vmcnt(8)` drains only the current tile's loads, which were
// issued one full K-step (32 MFMA + 16 ds_read) earlier -> no vmcnt(0) drain
// in the main loop (m218: counted-vs-drain0 is the lever, not dbuf itself).
// Fully unrolled t=0..15 so buffer indices & wait counts are compile-time.
// LDS 64KB -> 2 blocks/CU; grid supplies only 2 active blocks/CU anyway.
// Swizzle (rule #21): stored chunk p holds global chunk p^(row&7); LDS dest
// linear (global_load_lds constraint, m104), GLOBAL source pre-XOR'd, and
// ds_read applies the same XOR -> 2-way banks (free) instead of 16-way.
// Grid (128,8): blocks sharing an A-panel are spaced 128 in linear id ->
// same id%8 -> same XCD -> A re-reads hit that XCD's L2.
__global__ void __launch_bounds__(256)
rse_gemm6(const int* __restrict__ n_agent_p, const int* __restrict__ orig,
          const __hip_bfloat16* __restrict__ Xc,
          const __hip_bfloat16* __restrict__ Rb,
          float* __restrict__ out) {
    const int na = *n_agent_p;
    const int m0 = blockIdx.x * 128;     // compacted-row tile
    if (m0 >= na) return;                // early-exit past agent count
    const int n0 = blockIdx.y * 128;

    __shared__ __hip_bfloat16 As[2][128 * 64];
    __shared__ __hip_bfloat16 Bs[2][128 * 64];
    __shared__ int s_orig[128];

    const int tid  = threadIdx.x;
    const int lane = tid & 63;
    const int wave = tid >> 6;
    const int quad = lane >> 4;
    const int l15  = lane & 15;
    const int wr   = wave >> 1;
    const int wc   = wave & 1;

    if (tid < 128) {
        const int j = m0 + tid;
        s_orig[tid] = (j < na) ? orig[j] : -1;   // 1 extra vmcnt op for waves
    }                                            // 0/1: only strengthens waits

    // staging: each issue = 8 rows x 64 bf16 (1KB). lane -> row lane>>3,
    // stored chunk lane&7; global source chunk pre-XOR'd by row (rule #21).
    const int st_row = lane >> 3;
    const int st_k   = ((lane & 7) ^ st_row) * 8;   // bf16 units
    const __hip_bfloat16* aG = Xc + (size_t)m0 * DMODEL + st_k;
    const __hip_bfloat16* bG = Rb + (size_t)n0 * DMODEL + st_k;

#define STAGE(buf, k0)                                                        \
    do {                                                                      \
        _Pragma("unroll")                                                     \
        for (int q = 0; q < 4; ++q) {   /* A: 4 issues/wave (128 rows) */     \
            const int rg = (q * 4 + wave) * 8;                                \
            gload_lds16(aG + (size_t)(rg + st_row) * DMODEL + (k0),           \
                        &As[buf][rg * 64]);                                   \
        }                                                                     \
        _Pragma("unroll")                                                     \
        for (int q = 0; q < 4; ++q) {   /* B: 4 issues/wave (128 rows) */     \
            const int rg = (q * 4 + wave) * 8;                                \
            gload_lds16(bG + (size_t)(rg + st_row) * DMODEL + (k0),           \
                        &Bs[buf][rg * 64]);                                   \
        }                                                                     \
    } while (0)

    f32x4 acc[4][4] = {};

#define COMPUTE(buf)                                                          \
    do {                                                                      \
        _Pragma("unroll")                                                     \
        for (int kk = 0; kk < 2; ++kk) {                                      \
            short8 af[4], bfr[4];                                             \
            _Pragma("unroll")                                                 \
            for (int i = 0; i < 4; ++i) {                                     \
                const int r = wr * 64 + i * 16 + l15;                         \
                af[i] = *(const short8*)                                      \
                    &As[buf][r * 64 + ((kk * 4 + quad) ^ (r & 7)) * 8];       \
            }                                                                 \
            _Pragma("unroll")                                                 \
            for (int j = 0; j < 4; ++j) {                                     \
                const int r = wc * 64 + j * 16 + l15;                         \
                bfr[j] = *(const short8*)                                     \
                    &Bs[buf][r * 64 + ((kk * 4 + quad) ^ (r & 7)) * 8];       \
            }                                                                 \
            _Pragma("unroll")                                                 \
            for (int i = 0; i < 4; ++i)                                       \
                _Pragma("unroll")                                             \
                for (int j = 0; j < 4; ++j)                                   \
                    acc[i][j] = __builtin_amdgcn_mfma_f32_16x16x32_bf16(      \
                        af[i], bfr[j], acc[i][j], 0, 0, 0);                   \
        }                                                                     \
    } while (0)

    // prologue: two tiles in flight (depth-2)
    STAGE(0, 0);
    STAGE(1, 64);

    // 16 K-tiles, fully unrolled: buffer indices and wait counts are
    // compile-time constants.  Steady state per tile t:
    //   vmcnt(8): tile t's 8 loads done, tile t+1's 8 stay in flight
    //   barrier:  all waves agree tile t is resident
    //   COMPUTE(t&1)
    //   lgkmcnt(0)+sched_barrier+barrier: all ds_reads of buf done in every
    //     wave before any wave overwrites it (sched_barrier pins COMPUTE on
    //     this side — rule #18: "memory" doesn't order reg-only MFMA)
    //   STAGE(t&1, t+2): refill just-freed buffer, loads span next barrier
#pragma unroll
    for (int t = 0; t < 16; ++t) {
        if (t == 0)
            asm volatile("s_waitcnt vmcnt(8) lgkmcnt(0)" ::: "memory");
        else if (t < 15)
            asm volatile("s_waitcnt vmcnt(8)" ::: "memory");
        else
            asm volatile("s_waitcnt vmcnt(0)" ::: "memory");
        __builtin_amdgcn_s_barrier();
        COMPUTE(t & 1);
        if (t < 14) {
            asm volatile("s_waitcnt lgkmcnt(0)" ::: "memory");
            __builtin_amdgcn_sched_barrier(0);
            __builtin_amdgcn_s_barrier();
            STAGE(t & 1, (t + 2) * 64);
        }
    }
#undef STAGE
#undef COMPUTE

    // epilogue: C/D layout col=l15, row=quad*4+reg; scatter to orig token row
    const int colbase = n0 + wc * 64 + l15;
#pragma unroll
    for (int ti = 0; ti < 4; ++ti) {
        const int rowb = wr * 64 + ti * 16 + quad * 4;
#pragma unroll
        for (int r = 0; r < 4; ++r) {
            const int oj = s_orig[rowb + r];
            if (oj >= 0) {
                float* dst = out + (size_t)oj * DMODEL + colbase;
#pragma unroll
                for (int tj = 0; tj < 4; ++tj)
                    dst[tj * 16] = acc[ti][tj][r];
            }
        }
    }
}

extern "C" void kernel_launch(void* const* d_in, const int* in_sizes, int n_in,
                              void* d_out, int out_size, void* d_ws, size_t ws_size,
                              hipStream_t stream) {
    const int*   ids   = (const int*)d_in[0];
    const int*   roles = (const int*)d_in[1];
    const float* emb   = (const float*)d_in[2];
    const float* Rm    = (const float*)d_in[3];
    float*       out   = (float*)d_out;

    // ws layout: Xc 32MB | Rb 2MB | orig 64KB | n_agent 4B
    __hip_bfloat16* Xc = (__hip_bfloat16*)d_ws;
    __hip_bfloat16* Rb = Xc + (size_t)M_TOK * DMODEL;
    int* orig    = (int*)(Rb + (size_t)DMODEL * DMODEL);
    int* n_agent = orig + M_TOK;

    zero_ctr<<<1, 1, 0, stream>>>(n_agent);
    gather3<<<M_TOK / 16 + DMODEL / 16, 1024, 0, stream>>>(
        ids, roles, emb, Rm, Xc, Rb, out, orig, n_agent);
    dim3 grid2(M_TOK / 128, DMODEL / 128);   // (128, 8); early-exit past n_agent
    rse_gemm6<<<grid2, 256, 0, stream>>>(n_agent, orig, Xc, Rb, out);
}

// Round 5
// 309.692 us; speedup vs baseline: 1.0226x; 1.0226x over previous
//
#include <hip/hip_runtime.h>
#include <hip/hip_bf16.h>
#include <stdint.h>

// Problem constants (from reference)
#define DMODEL 1024
#define M_TOK  16384   // B*L = 4*4096

typedef __attribute__((ext_vector_type(8))) short short8;   // 8 x bf16 (4 VGPRs)
typedef __attribute__((ext_vector_type(4))) float f32x4;    // MFMA C/D frag

// Pack two fp32 -> two bf16 (RNE) in one dword via v_perm_b32.
__device__ __forceinline__ unsigned int pack2_bf16(float f0, float f1) {
    unsigned int u0 = __builtin_bit_cast(unsigned int, f0);
    unsigned int u1 = __builtin_bit_cast(unsigned int, f1);
    u0 += 0x7fffu + ((u0 >> 16) & 1u);
    u1 += 0x7fffu + ((u1 >> 16) & 1u);
    return __builtin_amdgcn_perm(u1, u0, 0x07060302);  // mem order f0, f1
}

// async global->LDS, 16B per lane. LDS dest = wave-uniform base + lane*16.
__device__ __forceinline__ void gload_lds16(const void* g, void* l) {
    __builtin_amdgcn_global_load_lds(
        (const __attribute__((address_space(1))) void*)g,
        (__attribute__((address_space(3))) void*)l, 16, 0, 0);
}

// ---------------- Phase 0: zero the compaction counter ----------------------
// ws is re-poisoned every call; graph-safe 1-thread zeroing (no memset node).
__global__ void zero_ctr(int* __restrict__ n_agent) { *n_agent = 0; }

// ---------------- Phase 1: gather + convert + atomic compaction -------------
// 1024 threads = 16 waves, one 1024-float row per wave. Block counts its
// agent rows, takes ONE atomicAdd for a contiguous slot range (order across
// blocks is nondeterministic, but each row's result is slot-independent).
// Agent rows -> bf16 Xc[slot]; user rows -> exact fp32 copy to out.
// Trailing 64 blocks convert R -> bf16 Rb.
__global__ void __launch_bounds__(1024)
gather3(const int* __restrict__ ids, const int* __restrict__ roles,
        const float* __restrict__ emb, const float* __restrict__ Rm,
        __hip_bfloat16* __restrict__ Xc, __hip_bfloat16* __restrict__ Rb,
        float* __restrict__ out, int* __restrict__ orig,
        int* __restrict__ n_agent) {
    __shared__ int s_cnt[16];
    __shared__ int s_slot[16];
    const int wave = threadIdx.x >> 6;
    const int lane = threadIdx.x & 63;
    const int blk  = blockIdx.x;
    if (blk < M_TOK / 16) {
        const int row  = blk * 16 + wave;
        const int id   = ids[row];                 // wave-uniform (s_load)
        const int role = roles[row];
        if (lane == 0) s_cnt[wave] = (role == 1);
        __syncthreads();
        if (threadIdx.x == 0) {
            int tot = 0, pre[16];
#pragma unroll
            for (int w = 0; w < 16; ++w) { pre[w] = tot; tot += s_cnt[w]; }
            const int base = atomicAdd(n_agent, tot);   // one atomic per block
#pragma unroll
            for (int w = 0; w < 16; ++w) s_slot[w] = base + pre[w];
        }
        __syncthreads();
        const float* src = emb + (size_t)id * DMODEL;
        if (role == 1) {
            const int slot = s_slot[wave];
            if (lane == 0) orig[slot] = row;
            unsigned short* dst = (unsigned short*)(Xc + (size_t)slot * DMODEL);
#pragma unroll
            for (int c = 0; c < 4; ++c) {
                const int idx = c * 256 + lane * 4;
                float4 v = *(const float4*)(src + idx);
                uint2 p = make_uint2(pack2_bf16(v.x, v.y), pack2_bf16(v.z, v.w));
                *(uint2*)(dst + idx) = p;
            }
        } else {
            float* dst = out + (size_t)row * DMODEL;
#pragma unroll
            for (int c = 0; c < 4; ++c) {
                const int idx = c * 256 + lane * 4;
                *(float4*)(dst + idx) = *(const float4*)(src + idx);
            }
        }
    } else {
        const int r = (blk - M_TOK / 16) * 16 + wave;
        const float* src = Rm + (size_t)r * DMODEL;
        unsigned short* dst = (unsigned short*)(Rb + (size_t)r * DMODEL);
#pragma unroll
        for (int c = 0; c < 4; ++c) {
            const int idx = c * 256 + lane * 4;
            float4 v = *(const float4*)(src + idx);
            uint2 p = make_uint2(pack2_bf16(v.x, v.y), pack2_bf16(v.z, v.w));
            *(uint2*)(dst + idx) = p;
        }
    }
}

// ---------------- Phase 2: bf16 GEMM over compacted agent rows --------------
// C[orig[j], e] = sum_d Xc[j,d] * R[e,d].  128x128 tile, BK=64 — the BEST
// MEASURED variant (r2: 309.9us).  r3 (64x128 dbuf) and r4 (depth-2 counted
// vmcnt) both landed within the +-3% cross-run noise band but not better;
// restored as-is.  LDS [row][64] with XOR chunk swizzle: stored chunk p holds
// global chunk p^(row&7).  Stage keeps the LDS dest LINEAR (global_load_lds
// constraint, m104) and pre-swizzles the GLOBAL source chunk; ds_read applies
// the same XOR -> 2-way banks (free) instead of 16-way.
// Grid (128,8): blocks sharing an A-panel are spaced 128 in linear id ->
// same id%8 -> same XCD -> A re-reads hit that XCD's L2.
__global__ void __launch_bounds__(256)
rse_gemm4(const int* __restrict__ n_agent_p, const int* __restrict__ orig,
          const __hip_bfloat16* __restrict__ Xc,
          const __hip_bfloat16* __restrict__ Rb,
          float* __restrict__ out) {
    const int na = *n_agent_p;
    const int m0 = blockIdx.x * 128;     // compacted-row tile
    if (m0 >= na) return;                // early-exit past agent count
    const int n0 = blockIdx.y * 128;

    __shared__ __hip_bfloat16 As[128 * 64];
    __shared__ __hip_bfloat16 Bs[128 * 64];
    __shared__ int s_orig[128];

    const int tid  = threadIdx.x;
    const int lane = tid & 63;
    const int wave = tid >> 6;
    const int quad = lane >> 4;
    const int l15  = lane & 15;
    const int wr   = wave >> 1;
    const int wc   = wave & 1;

    if (tid < 128) {
        const int j = m0 + tid;
        s_orig[tid] = (j < na) ? orig[j] : -1;
    }

    // staging: 8 lanes per 128B row-segment; 8 rows per 1KB issue.
    // LDS dest linear (base + lane*16); global chunk pre-swizzled by row.
    const int st_row = lane >> 3;                   // 0..7 within group
    const int st_k   = ((lane & 7) ^ st_row) * 8;   // XOR'd source chunk (bf16)
    const __hip_bfloat16* aG = Xc + (size_t)m0 * DMODEL + st_k;
    const __hip_bfloat16* bG = Rb + (size_t)n0 * DMODEL + st_k;

    f32x4 acc[4][4] = {};

    for (int k0 = 0; k0 < DMODEL; k0 += 64) {
        __syncthreads();   // previous tile's frag reads complete
#pragma unroll
        for (int q = 0; q < 4; ++q) {
            const int rg = (q * 4 + wave) * 8;      // 8-row group
            gload_lds16(aG + (size_t)(rg + st_row) * DMODEL + k0, &As[rg * 64]);
            gload_lds16(bG + (size_t)(rg + st_row) * DMODEL + k0, &Bs[rg * 64]);
        }
        __syncthreads();   // barrier drains vmcnt -> tile ready

#pragma unroll
        for (int kk = 0; kk < 2; ++kk) {
            short8 af[4], bfr[4];
#pragma unroll
            for (int i = 0; i < 4; ++i) {
                const int r = wr * 64 + i * 16 + l15;
                af[i] = *(const short8*)&As[r * 64 + ((kk * 4 + quad) ^ (r & 7)) * 8];
            }
#pragma unroll
            for (int j = 0; j < 4; ++j) {
                const int r = wc * 64 + j * 16 + l15;
                bfr[j] = *(const short8*)&Bs[r * 64 + ((kk * 4 + quad) ^ (r & 7)) * 8];
            }
#pragma unroll
            for (int i = 0; i < 4; ++i)
#pragma unroll
                for (int j = 0; j < 4; ++j)
                    acc[i][j] = __builtin_amdgcn_mfma_f32_16x16x32_bf16(af[i], bfr[j], acc[i][j], 0, 0, 0);
        }
    }

    // epilogue: C/D layout col=l15, row=quad*4+reg; scatter to orig token row
    const int colbase = n0 + wc * 64 + l15;
#pragma unroll
    for (int ti = 0; ti < 4; ++ti) {
        const int rowb = wr * 64 + ti * 16 + quad * 4;
#pragma unroll
        for (int r = 0; r < 4; ++r) {
            const int oj = s_orig[rowb + r];
            if (oj >= 0) {
                float* dst = out + (size_t)oj * DMODEL + colbase;
#pragma unroll
                for (int tj = 0; tj < 4; ++tj)
                    dst[tj * 16] = acc[ti][tj][r];
            }
        }
    }
}

extern "C" void kernel_launch(void* const* d_in, const int* in_sizes, int n_in,
                              void* d_out, int out_size, void* d_ws, size_t ws_size,
                              hipStream_t stream) {
    const int*   ids   = (const int*)d_in[0];
    const int*   roles = (const int*)d_in[1];
    const float* emb   = (const float*)d_in[2];
    const float* Rm    = (const float*)d_in[3];
    float*       out   = (float*)d_out;

    // ws layout: Xc 32MB | Rb 2MB | orig 64KB | n_agent 4B
    __hip_bfloat16* Xc = (__hip_bfloat16*)d_ws;
    __hip_bfloat16* Rb = Xc + (size_t)M_TOK * DMODEL;
    int* orig    = (int*)(Rb + (size_t)DMODEL * DMODEL);
    int* n_agent = orig + M_TOK;

    zero_ctr<<<1, 1, 0, stream>>>(n_agent);
    gather3<<<M_TOK / 16 + DMODEL / 16, 1024, 0, stream>>>(
        ids, roles, emb, Rm, Xc, Rb, out, orig, n_agent);
    dim3 grid2(M_TOK / 128, DMODEL / 128);   // (128, 8); early-exit past n_agent
    rse_gemm4<<<grid2, 256, 0, stream>>>(n_agent, orig, Xc, Rb, out);
}